// Round 9
// baseline (4957.445 us; speedup 1.0000x reference)
//
#include <hip/hip_runtime.h>
#include <cstdint>
#include <cstddef>

#define B_  512
#define S_  256
#define D_  768
#define K_  8
#define HB  256

// fp32(math.sqrt(768)) exactly as jax converts the python scalar (RN double->float).
#define SQRTD_F ((float)27.712812921102035)

// ---- P = X @ W^T + b (fp32, per-element single-accumulator k-ascending fmaf chain) ----
// BIT-EXACT per-element rounding vs CPU BLAS: one fp32 acc, FMA, strictly ascending k.
// Merged: blocks [0,tilesPerInput) = K projection; rest = Q projection (with /sqrt(D)).
// Block tile 256 rows x 128 cols, 256 threads, 8x16 per thread (cols tx*8 / 64+tx*8).
// SINGLE-buffered LDS (25.6KB), BK=16, 2 barriers/iter: staging regs don't overlap the
// FMA burst -> peak VGPR ~162 -> __launch_bounds__(256,3) = 3 blocks/CU, grid 768 = one
// clean round; exposed stage latency hidden by the other 2 waves/SIMD (TLP).
__global__ __launch_bounds__(256, 3) void kproj32(
    const float* __restrict__ Xk, const float* __restrict__ Xq,
    const float* __restrict__ Wk, const float* __restrict__ bk,
    const float* __restrict__ Wq, const float* __restrict__ bq,
    float* __restrict__ Kp, float* __restrict__ Qp, int tilesPerInput) {
  __shared__ __align__(16) float Xs[16][264]; // [kk][row 0..255], pad 264
  __shared__ __align__(16) float Ws[16][136]; // [kk][col 0..127], pad 136
  int bid = blockIdx.x;
  int divq = 0;
  const float *X, *W, *bias;
  float* P;
  if (bid < tilesPerInput) { X = Xk; W = Wk; bias = bk; P = Kp; }
  else { bid -= tilesPerInput; X = Xq; W = Wq; bias = bq; P = Qp; divq = 1; }
  int mt = bid / 6, nt = bid % 6;
  int m0 = mt * 256, n0 = nt * 128;
  int tid = threadIdx.x;
  int tx = tid & 7, ty = tid >> 3;          // compute: rows ty*8+i, cols tx*8+j / 64+tx*8+j
  int wc = tid & 127, wq = (tid >> 7) * 8;  // staging: W col wc, k-8-group wq
  const float* Xp = X + (size_t)(m0 + tid) * D_;       // staging: X row = tid, 16 k/iter
  const float* Wp = W + (size_t)(n0 + wc) * D_ + wq;   // staging: 8 k/iter
  float acc[8][16] = {};

  for (int kt = 0; kt < D_; kt += 16) {     // ascending k blocks
    { // stage k-block [kt, kt+16) -> LDS (single buffer)
      float4 x0 = *(const float4*)(Xp + kt);
      float4 x1 = *(const float4*)(Xp + kt + 4);
      float4 x2 = *(const float4*)(Xp + kt + 8);
      float4 x3 = *(const float4*)(Xp + kt + 12);
      float4 w0 = *(const float4*)(Wp + kt);
      float4 w1 = *(const float4*)(Wp + kt + 4);
      Xs[ 0][tid] = x0.x; Xs[ 1][tid] = x0.y; Xs[ 2][tid] = x0.z; Xs[ 3][tid] = x0.w;
      Xs[ 4][tid] = x1.x; Xs[ 5][tid] = x1.y; Xs[ 6][tid] = x1.z; Xs[ 7][tid] = x1.w;
      Xs[ 8][tid] = x2.x; Xs[ 9][tid] = x2.y; Xs[10][tid] = x2.z; Xs[11][tid] = x2.w;
      Xs[12][tid] = x3.x; Xs[13][tid] = x3.y; Xs[14][tid] = x3.z; Xs[15][tid] = x3.w;
      Ws[wq + 0][wc] = w0.x; Ws[wq + 1][wc] = w0.y;
      Ws[wq + 2][wc] = w0.z; Ws[wq + 3][wc] = w0.w;
      Ws[wq + 4][wc] = w1.x; Ws[wq + 5][wc] = w1.y;
      Ws[wq + 6][wc] = w1.z; Ws[wq + 7][wc] = w1.w;
    }
    __syncthreads();                         // LDS ready
    #pragma unroll
    for (int kk = 0; kk < 16; ++kk) {        // ascending k within block
      float xv[8], wv[16];
      *(float4*)(xv)      = *(const float4*)(&Xs[kk][ty * 8]);
      *(float4*)(xv + 4)  = *(const float4*)(&Xs[kk][ty * 8 + 4]);
      *(float4*)(wv)      = *(const float4*)(&Ws[kk][tx * 8]);
      *(float4*)(wv + 4)  = *(const float4*)(&Ws[kk][tx * 8 + 4]);
      *(float4*)(wv + 8)  = *(const float4*)(&Ws[kk][64 + tx * 8]);
      *(float4*)(wv + 12) = *(const float4*)(&Ws[kk][64 + tx * 8 + 4]);
      #pragma unroll
      for (int i = 0; i < 8; ++i)
        #pragma unroll
        for (int j = 0; j < 16; ++j)
          acc[i][j] = fmaf(xv[i], wv[j], acc[i][j]); // single accumulator per element
    }
    __syncthreads();                         // all reads done before next stage
  }

  #pragma unroll
  for (int i = 0; i < 8; ++i) {
    float* pp = P + (size_t)(m0 + ty * 8 + i) * D_ + n0;
    float o[16];
    #pragma unroll
    for (int j = 0; j < 8; ++j) {
      float v = acc[i][j] + bias[n0 + tx * 8 + j];        // fp32 bias add, as ref
      if (divq) v = v / SQRTD_F;                           // IEEE fp32 division, as ref
      o[j] = v;
    }
    #pragma unroll
    for (int j = 0; j < 8; ++j) {
      float v = acc[i][8 + j] + bias[n0 + 64 + tx * 8 + j];
      if (divq) v = v / SQRTD_F;
      o[8 + j] = v;
    }
    *(float4*)(pp + tx * 8)          = *(float4*)(o);
    *(float4*)(pp + tx * 8 + 4)      = *(float4*)(o + 4);
    *(float4*)(pp + 64 + tx * 8)     = *(float4*)(o + 8);
    *(float4*)(pp + 64 + tx * 8 + 4) = *(float4*)(o + 12);
  }
}

// ---- scores[r,m] = fmaf-chain_d( Qp[r,d]*Kp[m,d] ), fp32; in-register top-8 + histogram ----
// Block = (local batch lb, 32-row q-tile). 256 thr; group ty (of 32 lanes) owns rows ty*4+i;
// lane tx owns keys {tx*4+j, 128+tx*4+j}. BK=16 double-buffered. Bit-exact fp32 chains.
__global__ __launch_bounds__(256) void kscore32(
    const float* __restrict__ Qp, const float* __restrict__ Kp,
    int* __restrict__ count, int bBase) {
  __shared__ __align__(16) float Ts[2][16][36];   // [buf][kk][row]
  __shared__ __align__(16) float Ks[2][16][260];  // [buf][kk][key]
  __shared__ int hist[256];
  int lb = blockIdx.x / 8, qt = blockIdx.x % 8;
  int b = bBase + lb;
  int tid = threadIdx.x;
  hist[tid] = 0;
  int tx = tid % 32, ty = tid / 32;
  int qr_ = tid / 4, qq = (tid % 4) * 4;  // Q staging (threads 0..127)
  const float* Qrow = Qp + (size_t)(lb * S_ + qt * 32 + qr_) * D_ + qq;
  const float* Krow = Kp + (size_t)(lb * S_ + tid) * D_;
  float acc[4][8] = {};
  float4 qreg = {0, 0, 0, 0};
  float4 kreg0, kreg1, kreg2, kreg3;

  // prologue: load k-block 0, write LDS[0]
  if (tid < 128) qreg = *(const float4*)(Qrow);
  kreg0 = *(const float4*)(Krow);
  kreg1 = *(const float4*)(Krow + 4);
  kreg2 = *(const float4*)(Krow + 8);
  kreg3 = *(const float4*)(Krow + 12);
  if (tid < 128) {
    Ts[0][qq + 0][qr_] = qreg.x; Ts[0][qq + 1][qr_] = qreg.y;
    Ts[0][qq + 2][qr_] = qreg.z; Ts[0][qq + 3][qr_] = qreg.w;
  }
  {
    Ks[0][ 0][tid] = kreg0.x; Ks[0][ 1][tid] = kreg0.y;
    Ks[0][ 2][tid] = kreg0.z; Ks[0][ 3][tid] = kreg0.w;
    Ks[0][ 4][tid] = kreg1.x; Ks[0][ 5][tid] = kreg1.y;
    Ks[0][ 6][tid] = kreg1.z; Ks[0][ 7][tid] = kreg1.w;
    Ks[0][ 8][tid] = kreg2.x; Ks[0][ 9][tid] = kreg2.y;
    Ks[0][10][tid] = kreg2.z; Ks[0][11][tid] = kreg2.w;
    Ks[0][12][tid] = kreg3.x; Ks[0][13][tid] = kreg3.y;
    Ks[0][14][tid] = kreg3.z; Ks[0][15][tid] = kreg3.w;
  }

  for (int kt = 0; kt < D_; kt += 16) {   // ascending d blocks
    __syncthreads();
    int buf = (kt >> 4) & 1;
    bool pre = (kt + 16) < D_;
    if (pre) {
      if (tid < 128) qreg = *(const float4*)(Qrow + kt + 16);
      kreg0 = *(const float4*)(Krow + kt + 16);
      kreg1 = *(const float4*)(Krow + kt + 20);
      kreg2 = *(const float4*)(Krow + kt + 24);
      kreg3 = *(const float4*)(Krow + kt + 28);
    }
    #pragma unroll
    for (int kk = 0; kk < 16; ++kk) {     // ascending d within block
      float tv[4], kv[8];
      *(float4*)(tv)     = *(const float4*)(&Ts[buf][kk][ty * 4]);
      *(float4*)(kv)     = *(const float4*)(&Ks[buf][kk][tx * 4]);
      *(float4*)(kv + 4) = *(const float4*)(&Ks[buf][kk][128 + tx * 4]);
      #pragma unroll
      for (int i = 0; i < 4; ++i)
        #pragma unroll
        for (int j = 0; j < 8; ++j)
          acc[i][j] = fmaf(tv[i], kv[j], acc[i][j]); // single accumulator per element
    }
    if (pre) {
      int nb = buf ^ 1;
      if (tid < 128) {
        Ts[nb][qq + 0][qr_] = qreg.x; Ts[nb][qq + 1][qr_] = qreg.y;
        Ts[nb][qq + 2][qr_] = qreg.z; Ts[nb][qq + 3][qr_] = qreg.w;
      }
      Ks[nb][ 0][tid] = kreg0.x; Ks[nb][ 1][tid] = kreg0.y;
      Ks[nb][ 2][tid] = kreg0.z; Ks[nb][ 3][tid] = kreg0.w;
      Ks[nb][ 4][tid] = kreg1.x; Ks[nb][ 5][tid] = kreg1.y;
      Ks[nb][ 6][tid] = kreg1.z; Ks[nb][ 7][tid] = kreg1.w;
      Ks[nb][ 8][tid] = kreg2.x; Ks[nb][ 9][tid] = kreg2.y;
      Ks[nb][10][tid] = kreg2.z; Ks[nb][11][tid] = kreg2.w;
      Ks[nb][12][tid] = kreg3.x; Ks[nb][13][tid] = kreg3.y;
      Ks[nb][14][tid] = kreg3.z; Ks[nb][15][tid] = kreg3.w;
    }
  }

  // top-8 per row; tie -> lower index (matches jax.lax.top_k on monotone softmax image).
  for (int i = 0; i < 4; ++i) {
    unsigned live = 0xffu;
    #pragma unroll
    for (int it = 0; it < 8; ++it) {
      float bv = -3.4e38f; int bi = 1 << 30;
      #pragma unroll
      for (int j = 0; j < 8; ++j) {
        if ((live >> j) & 1u) {
          float v = acc[i][j];
          int idx = (j < 4) ? (tx * 4 + j) : (128 + tx * 4 + (j - 4));
          if (v > bv || (v == bv && idx < bi)) { bv = v; bi = idx; }
        }
      }
      #pragma unroll
      for (int off = 1; off < 32; off <<= 1) { // closed within the 32-lane group
        float ov = __shfl_xor(bv, off);
        int   oi = __shfl_xor(bi, off);
        if (ov > bv || (ov == bv && oi < bi)) { bv = ov; bi = oi; }
      }
      int owner, jj;
      if (bi < 128) { owner = bi >> 2; jj = bi & 3; }
      else          { owner = (bi - 128) >> 2; jj = 4 + ((bi - 128) & 3); }
      if (tx == owner) live &= ~(1u << jj);
      if (tx == 0) atomicAdd(&hist[bi], 1);
    }
  }
  __syncthreads();
  if (hist[tid] > 0) atomicAdd(&count[(size_t)b * HB + tid], hist[tid]);
}

// ---- final: per-batch top-8 of counts (exact integers), tie-break lower index ----
__global__ __launch_bounds__(64) void kfinal(const int* __restrict__ count, int* __restrict__ out) {
  int b = blockIdx.x;
  int lane = threadIdx.x;
  int c[4];
  #pragma unroll
  for (int j = 0; j < 4; ++j) c[j] = count[(size_t)b * HB + lane + 64 * j];
  #pragma unroll
  for (int it = 0; it < 8; ++it) {
    int bk = -0x7fffffff;
    #pragma unroll
    for (int j = 0; j < 4; ++j) {
      int idx = lane + 64 * j;
      int key = c[j] * 256 + (255 - idx); // removed entries (c=-1) go negative, never win
      if (key > bk) bk = key;
    }
    #pragma unroll
    for (int off = 1; off < 64; off <<= 1) {
      int ok = __shfl_xor(bk, off);
      if (ok > bk) bk = ok;
    }
    int idx = 255 - (bk & 255);
    if (lane == (idx & 63)) c[idx >> 6] = -1;
    if (lane == 0) out[b * K_ + it] = idx;
  }
}

extern "C" void kernel_launch(void* const* d_in, const int* in_sizes, int n_in,
                              void* d_out, int out_size, void* d_ws, size_t ws_size,
                              hipStream_t stream) {
  const float* k_in = (const float*)d_in[0];
  const float* q_in = (const float*)d_in[2];
  const float* Wk   = (const float*)d_in[4];
  const float* bk   = (const float*)d_in[5];
  const float* Wq   = (const float*)d_in[8];
  const float* bq   = (const float*)d_in[9];
  // v/Wv/bv dead; mask all-true; softmax monotone in fp32 (equal scores -> equal attention,
  // same lower-index tie) => top-k on scores. Pipeline = reference verbatim, in fp32 with
  // BLAS-equivalent per-element rounding (single-acc ascending-k FMA chains):
  //   Kp = k_in@Wk^T + bk ; Qp = (q_in@Wq^T + bq) / f32(sqrt(768)) ; scores = Qp@Kp^T.

  char* ws = (char*)d_ws;
  int* cnt = (int*)ws;                 // 512*256*4 = 524288 B
  const size_t offQ = 524288;

  // CB=64: per-chunk working set ~200 MB -> L3-resident (R7 lesson: 400+ MB thrashes L3).
  int CB = 64;
  while (CB > 1 && offQ + 2 * (size_t)CB * S_ * D_ * 4 > ws_size) CB >>= 1;
  const int nchunks = B_ / CB;
  float* Qp = (float*)(ws + offQ);
  float* Kp = Qp + (size_t)CB * S_ * D_;

  hipMemsetAsync(cnt, 0, (size_t)B_ * HB * 4, stream);

  for (int c = 0; c < nchunks; ++c) {
    const float* kc = k_in + (size_t)c * CB * S_ * D_;
    const float* qc = q_in + (size_t)c * CB * S_ * D_;
    // tilesPerInput = (CB*256/256 rows) * (768/128 cols) = CB*6; grid 768 = 3/CU, one round
    kproj32<<<CB * 12, 256, 0, stream>>>(kc, qc, Wk, bk, Wq, bq, Kp, Qp, CB * 6);
    kscore32<<<CB * 8, 256, 0, stream>>>(Qp, Kp, cnt, c * CB);
  }
  kfinal<<<B_, 64, 0, stream>>>(cnt, (int*)d_out);
}

// Round 10
// 4713.799 us; speedup vs baseline: 1.0517x; 1.0517x over previous
//
#include <hip/hip_runtime.h>
#include <cstdint>
#include <cstddef>

#define B_  512
#define S_  256
#define D_  768
#define K_  8
#define HB  256

// fp32(math.sqrt(768)) exactly as jax converts the python scalar (RN double->float).
#define SQRTD_F ((float)27.712812921102035)

// ---- P = X @ W^T + b (fp32, per-element single-accumulator k-ascending fmaf chain) ----
// BIT-EXACT per-element rounding vs CPU BLAS: one fp32 acc, FMA, strictly ascending k.
// Merged: blocks [0,tilesPerInput) = K projection; rest = Q projection (with /sqrt(D)).
// Block tile 128 rows x 256 cols (3 col-tiles -> X re-read 3x, was 6x at 128-col tiles),
// 256 threads, 8x16 per thread (cols tx*8 / 128+tx*8). BK=8 double-buffered.
// acc=128 VGPR -> __launch_bounds__(256,2); R9 lesson: 3 waves/SIMD spills this acc.
__global__ __launch_bounds__(256, 2) void kproj32(
    const float* __restrict__ Xk, const float* __restrict__ Xq,
    const float* __restrict__ Wk, const float* __restrict__ bk,
    const float* __restrict__ Wq, const float* __restrict__ bq,
    float* __restrict__ Kp, float* __restrict__ Qp, int tilesPerInput) {
  __shared__ __align__(16) float Xs[2][8][136]; // [buf][kk][row 0..127], pad 136
  __shared__ __align__(16) float Ws[2][8][264]; // [buf][kk][col 0..255], pad 264
  int bid = blockIdx.x;
  int divq = 0;
  const float *X, *W, *bias;
  float* P;
  if (bid < tilesPerInput) { X = Xk; W = Wk; bias = bk; P = Kp; }
  else { bid -= tilesPerInput; X = Xq; W = Wq; bias = bq; P = Qp; divq = 1; }
  int mt = bid / 3, nt = bid % 3;
  int m0 = mt * 128, n0 = nt * 256;
  int tid = threadIdx.x;
  int tx = tid & 15, ty = tid >> 4;           // compute: rows ty*8+i, cols tx*8+j / 128+tx*8+j
  int xr = tid & 127, xq = (tid >> 7) * 4;    // staging X: row xr, k-quad xq (1 float4)
  const float* Xp = X + (size_t)(m0 + xr) * D_ + xq;
  const float* Wp = W + (size_t)(n0 + tid) * D_;      // staging W: col tid, 8 k (2 float4)
  float acc[8][16] = {};
  float4 xa, wa, wb;

  // prologue: k-block 0 -> LDS[0]
  xa = *(const float4*)(Xp);
  wa = *(const float4*)(Wp);
  wb = *(const float4*)(Wp + 4);
  Xs[0][xq + 0][xr] = xa.x; Xs[0][xq + 1][xr] = xa.y;
  Xs[0][xq + 2][xr] = xa.z; Xs[0][xq + 3][xr] = xa.w;
  Ws[0][0][tid] = wa.x; Ws[0][1][tid] = wa.y; Ws[0][2][tid] = wa.z; Ws[0][3][tid] = wa.w;
  Ws[0][4][tid] = wb.x; Ws[0][5][tid] = wb.y; Ws[0][6][tid] = wb.z; Ws[0][7][tid] = wb.w;

  for (int kt = 0; kt < D_; kt += 8) {      // ascending k blocks
    __syncthreads();
    int buf = (kt >> 3) & 1;
    bool pre = (kt + 8) < D_;
    if (pre) {                               // prefetch next block into regs
      xa = *(const float4*)(Xp + kt + 8);
      wa = *(const float4*)(Wp + kt + 8);
      wb = *(const float4*)(Wp + kt + 12);
    }
    #pragma unroll
    for (int kk = 0; kk < 8; ++kk) {         // ascending k within block
      float xv[8], wv[16];
      *(float4*)(xv)      = *(const float4*)(&Xs[buf][kk][ty * 8]);
      *(float4*)(xv + 4)  = *(const float4*)(&Xs[buf][kk][ty * 8 + 4]);
      *(float4*)(wv)      = *(const float4*)(&Ws[buf][kk][tx * 8]);
      *(float4*)(wv + 4)  = *(const float4*)(&Ws[buf][kk][tx * 8 + 4]);
      *(float4*)(wv + 8)  = *(const float4*)(&Ws[buf][kk][128 + tx * 8]);
      *(float4*)(wv + 12) = *(const float4*)(&Ws[buf][kk][128 + tx * 8 + 4]);
      #pragma unroll
      for (int i = 0; i < 8; ++i)
        #pragma unroll
        for (int j = 0; j < 16; ++j)
          acc[i][j] = fmaf(xv[i], wv[j], acc[i][j]); // single accumulator per element
    }
    if (pre) {                               // write next block to alternate buffer
      int nb = buf ^ 1;
      Xs[nb][xq + 0][xr] = xa.x; Xs[nb][xq + 1][xr] = xa.y;
      Xs[nb][xq + 2][xr] = xa.z; Xs[nb][xq + 3][xr] = xa.w;
      Ws[nb][0][tid] = wa.x; Ws[nb][1][tid] = wa.y; Ws[nb][2][tid] = wa.z; Ws[nb][3][tid] = wa.w;
      Ws[nb][4][tid] = wb.x; Ws[nb][5][tid] = wb.y; Ws[nb][6][tid] = wb.z; Ws[nb][7][tid] = wb.w;
    }
  }

  #pragma unroll
  for (int i = 0; i < 8; ++i) {
    float* pp = P + (size_t)(m0 + ty * 8 + i) * D_ + n0;
    float o[16];
    #pragma unroll
    for (int j = 0; j < 8; ++j) {
      float v = acc[i][j] + bias[n0 + tx * 8 + j];         // fp32 bias add, as ref
      if (divq) v = v / SQRTD_F;                            // IEEE fp32 division, as ref
      o[j] = v;
    }
    #pragma unroll
    for (int j = 0; j < 8; ++j) {
      float v = acc[i][8 + j] + bias[n0 + 128 + tx * 8 + j];
      if (divq) v = v / SQRTD_F;
      o[8 + j] = v;
    }
    *(float4*)(pp + tx * 8)           = *(float4*)(o);
    *(float4*)(pp + tx * 8 + 4)       = *(float4*)(o + 4);
    *(float4*)(pp + 128 + tx * 8)     = *(float4*)(o + 8);
    *(float4*)(pp + 128 + tx * 8 + 4) = *(float4*)(o + 12);
  }
}

// ---- scores[r,m] = fmaf-chain_d( Qp[r,d]*Kp[m,d] ), fp32; in-register top-8 + histogram ----
// Block = (local batch lb, 32-row q-tile). 256 thr; group ty (of 32 lanes) owns rows ty*4+i;
// lane tx owns keys {tx*4+j, 128+tx*4+j}. BK=16 double-buffered. Bit-exact fp32 chains.
__global__ __launch_bounds__(256) void kscore32(
    const float* __restrict__ Qp, const float* __restrict__ Kp,
    int* __restrict__ count, int bBase) {
  __shared__ __align__(16) float Ts[2][16][36];   // [buf][kk][row]
  __shared__ __align__(16) float Ks[2][16][260];  // [buf][kk][key]
  __shared__ int hist[256];
  int lb = blockIdx.x / 8, qt = blockIdx.x % 8;
  int b = bBase + lb;
  int tid = threadIdx.x;
  hist[tid] = 0;
  int tx = tid % 32, ty = tid / 32;
  int qr_ = tid / 4, qq = (tid % 4) * 4;  // Q staging (threads 0..127)
  const float* Qrow = Qp + (size_t)(lb * S_ + qt * 32 + qr_) * D_ + qq;
  const float* Krow = Kp + (size_t)(lb * S_ + tid) * D_;
  float acc[4][8] = {};
  float4 qreg = {0, 0, 0, 0};
  float4 kreg0, kreg1, kreg2, kreg3;

  // prologue: load k-block 0, write LDS[0]
  if (tid < 128) qreg = *(const float4*)(Qrow);
  kreg0 = *(const float4*)(Krow);
  kreg1 = *(const float4*)(Krow + 4);
  kreg2 = *(const float4*)(Krow + 8);
  kreg3 = *(const float4*)(Krow + 12);
  if (tid < 128) {
    Ts[0][qq + 0][qr_] = qreg.x; Ts[0][qq + 1][qr_] = qreg.y;
    Ts[0][qq + 2][qr_] = qreg.z; Ts[0][qq + 3][qr_] = qreg.w;
  }
  {
    Ks[0][ 0][tid] = kreg0.x; Ks[0][ 1][tid] = kreg0.y;
    Ks[0][ 2][tid] = kreg0.z; Ks[0][ 3][tid] = kreg0.w;
    Ks[0][ 4][tid] = kreg1.x; Ks[0][ 5][tid] = kreg1.y;
    Ks[0][ 6][tid] = kreg1.z; Ks[0][ 7][tid] = kreg1.w;
    Ks[0][ 8][tid] = kreg2.x; Ks[0][ 9][tid] = kreg2.y;
    Ks[0][10][tid] = kreg2.z; Ks[0][11][tid] = kreg2.w;
    Ks[0][12][tid] = kreg3.x; Ks[0][13][tid] = kreg3.y;
    Ks[0][14][tid] = kreg3.z; Ks[0][15][tid] = kreg3.w;
  }

  for (int kt = 0; kt < D_; kt += 16) {   // ascending d blocks
    __syncthreads();
    int buf = (kt >> 4) & 1;
    bool pre = (kt + 16) < D_;
    if (pre) {
      if (tid < 128) qreg = *(const float4*)(Qrow + kt + 16);
      kreg0 = *(const float4*)(Krow + kt + 16);
      kreg1 = *(const float4*)(Krow + kt + 20);
      kreg2 = *(const float4*)(Krow + kt + 24);
      kreg3 = *(const float4*)(Krow + kt + 28);
    }
    #pragma unroll
    for (int kk = 0; kk < 16; ++kk) {     // ascending d within block
      float tv[4], kv[8];
      *(float4*)(tv)     = *(const float4*)(&Ts[buf][kk][ty * 4]);
      *(float4*)(kv)     = *(const float4*)(&Ks[buf][kk][tx * 4]);
      *(float4*)(kv + 4) = *(const float4*)(&Ks[buf][kk][128 + tx * 4]);
      #pragma unroll
      for (int i = 0; i < 4; ++i)
        #pragma unroll
        for (int j = 0; j < 8; ++j)
          acc[i][j] = fmaf(tv[i], kv[j], acc[i][j]); // single accumulator per element
    }
    if (pre) {
      int nb = buf ^ 1;
      if (tid < 128) {
        Ts[nb][qq + 0][qr_] = qreg.x; Ts[nb][qq + 1][qr_] = qreg.y;
        Ts[nb][qq + 2][qr_] = qreg.z; Ts[nb][qq + 3][qr_] = qreg.w;
      }
      Ks[nb][ 0][tid] = kreg0.x; Ks[nb][ 1][tid] = kreg0.y;
      Ks[nb][ 2][tid] = kreg0.z; Ks[nb][ 3][tid] = kreg0.w;
      Ks[nb][ 4][tid] = kreg1.x; Ks[nb][ 5][tid] = kreg1.y;
      Ks[nb][ 6][tid] = kreg1.z; Ks[nb][ 7][tid] = kreg1.w;
      Ks[nb][ 8][tid] = kreg2.x; Ks[nb][ 9][tid] = kreg2.y;
      Ks[nb][10][tid] = kreg2.z; Ks[nb][11][tid] = kreg2.w;
      Ks[nb][12][tid] = kreg3.x; Ks[nb][13][tid] = kreg3.y;
      Ks[nb][14][tid] = kreg3.z; Ks[nb][15][tid] = kreg3.w;
    }
  }

  // top-8 per row; tie -> lower index (matches jax.lax.top_k on monotone softmax image).
  for (int i = 0; i < 4; ++i) {
    unsigned live = 0xffu;
    #pragma unroll
    for (int it = 0; it < 8; ++it) {
      float bv = -3.4e38f; int bi = 1 << 30;
      #pragma unroll
      for (int j = 0; j < 8; ++j) {
        if ((live >> j) & 1u) {
          float v = acc[i][j];
          int idx = (j < 4) ? (tx * 4 + j) : (128 + tx * 4 + (j - 4));
          if (v > bv || (v == bv && idx < bi)) { bv = v; bi = idx; }
        }
      }
      #pragma unroll
      for (int off = 1; off < 32; off <<= 1) { // closed within the 32-lane group
        float ov = __shfl_xor(bv, off);
        int   oi = __shfl_xor(bi, off);
        if (ov > bv || (ov == bv && oi < bi)) { bv = ov; bi = oi; }
      }
      int owner, jj;
      if (bi < 128) { owner = bi >> 2; jj = bi & 3; }
      else          { owner = (bi - 128) >> 2; jj = 4 + ((bi - 128) & 3); }
      if (tx == owner) live &= ~(1u << jj);
      if (tx == 0) atomicAdd(&hist[bi], 1);
    }
  }
  __syncthreads();
  if (hist[tid] > 0) atomicAdd(&count[(size_t)b * HB + tid], hist[tid]);
}

// ---- final: per-batch top-8 of counts (exact integers), tie-break lower index ----
__global__ __launch_bounds__(64) void kfinal(const int* __restrict__ count, int* __restrict__ out) {
  int b = blockIdx.x;
  int lane = threadIdx.x;
  int c[4];
  #pragma unroll
  for (int j = 0; j < 4; ++j) c[j] = count[(size_t)b * HB + lane + 64 * j];
  #pragma unroll
  for (int it = 0; it < 8; ++it) {
    int bk = -0x7fffffff;
    #pragma unroll
    for (int j = 0; j < 4; ++j) {
      int idx = lane + 64 * j;
      int key = c[j] * 256 + (255 - idx); // removed entries (c=-1) go negative, never win
      if (key > bk) bk = key;
    }
    #pragma unroll
    for (int off = 1; off < 64; off <<= 1) {
      int ok = __shfl_xor(bk, off);
      if (ok > bk) bk = ok;
    }
    int idx = 255 - (bk & 255);
    if (lane == (idx & 63)) c[idx >> 6] = -1;
    if (lane == 0) out[b * K_ + it] = idx;
  }
}

extern "C" void kernel_launch(void* const* d_in, const int* in_sizes, int n_in,
                              void* d_out, int out_size, void* d_ws, size_t ws_size,
                              hipStream_t stream) {
  const float* k_in = (const float*)d_in[0];
  const float* q_in = (const float*)d_in[2];
  const float* Wk   = (const float*)d_in[4];
  const float* bk   = (const float*)d_in[5];
  const float* Wq   = (const float*)d_in[8];
  const float* bq   = (const float*)d_in[9];
  // v/Wv/bv dead; mask all-true; softmax monotone in fp32 (equal scores -> equal attention,
  // same lower-index tie) => top-k on scores. Pipeline = reference verbatim, in fp32 with
  // BLAS-equivalent per-element rounding (single-acc ascending-k FMA chains):
  //   Kp = k_in@Wk^T + bk ; Qp = (q_in@Wq^T + bq) / f32(sqrt(768)) ; scores = Qp@Kp^T.

  char* ws = (char*)d_ws;
  int* cnt = (int*)ws;                 // 512*256*4 = 524288 B
  const size_t offQ = 524288;

  // CB=64: per-chunk working set ~200 MB -> L3-resident (R7 lesson: 400+ MB thrashes L3).
  int CB = 64;
  while (CB > 1 && offQ + 2 * (size_t)CB * S_ * D_ * 4 > ws_size) CB >>= 1;
  const int nchunks = B_ / CB;
  float* Qp = (float*)(ws + offQ);
  float* Kp = Qp + (size_t)CB * S_ * D_;

  hipMemsetAsync(cnt, 0, (size_t)B_ * HB * 4, stream);

  for (int c = 0; c < nchunks; ++c) {
    const float* kc = k_in + (size_t)c * CB * S_ * D_;
    const float* qc = q_in + (size_t)c * CB * S_ * D_;
    // tilesPerInput = (CB*256/128 rows) * (768/256 cols) = CB*6
    kproj32<<<CB * 12, 256, 0, stream>>>(kc, qc, Wk, bk, Wq, bq, Kp, Qp, CB * 6);
    kscore32<<<CB * 8, 256, 0, stream>>>(Qp, Kp, cnt, c * CB);
  }
  kfinal<<<B_, 64, 0, stream>>>(cnt, (int*)d_out);
}

// Round 11
// 4657.773 us; speedup vs baseline: 1.0643x; 1.0120x over previous
//
#include <hip/hip_runtime.h>
#include <cstdint>
#include <cstddef>

#define B_  512
#define S_  256
#define D_  768
#define K_  8
#define HB  256

// fp32(math.sqrt(768)) exactly as jax converts the python scalar (RN double->float).
#define SQRTD_F ((float)27.712812921102035)

// ---- P = X @ W^T + b (fp32, per-element single-accumulator k-ascending fmaf chain) ----
// BIT-EXACT per-element rounding vs CPU BLAS: one fp32 acc, FMA, strictly ascending k.
// Merged: blocks [0,tilesPerInput) = K projection; rest = Q projection (with /sqrt(D)).
// Block tile 128 rows x 256 cols (X re-read 3x), 256 threads, 8 rows x 16 cols per thread.
// Col ownership = 4 groups of 4: {g*64 + tx*4}, tx in 0..15 -> Ws reads at stride 16B span
// 256B = 2 bank-wraps = 2-way = free (R10's 2 groups of 8 spanned 512B = 4-way conflict).
// BK=8 double-buffered. acc=128 VGPR -> __launch_bounds__(256,2) (R9: 3 waves spills).
__global__ __launch_bounds__(256, 2) void kproj32(
    const float* __restrict__ Xk, const float* __restrict__ Xq,
    const float* __restrict__ Wk, const float* __restrict__ bk,
    const float* __restrict__ Wq, const float* __restrict__ bq,
    float* __restrict__ Kp, float* __restrict__ Qp, int tilesPerInput) {
  __shared__ __align__(16) float Xs[2][8][136]; // [buf][kk][row 0..127], pad 136
  __shared__ __align__(16) float Ws[2][8][264]; // [buf][kk][col 0..255], pad 264
  int bid = blockIdx.x;
  int divq = 0;
  const float *X, *W, *bias;
  float* P;
  if (bid < tilesPerInput) { X = Xk; W = Wk; bias = bk; P = Kp; }
  else { bid -= tilesPerInput; X = Xq; W = Wq; bias = bq; P = Qp; divq = 1; }
  int mt = bid / 3, nt = bid % 3;
  int m0 = mt * 128, n0 = nt * 256;
  int tid = threadIdx.x;
  int tx = tid & 15, ty = tid >> 4;           // compute: rows ty*8+i, cols g*64+tx*4+j (g<4)
  int xr = tid & 127, xq = (tid >> 7) * 4;    // staging X: row xr, k-quad xq (1 float4)
  const float* Xp = X + (size_t)(m0 + xr) * D_ + xq;
  const float* Wp = W + (size_t)(n0 + tid) * D_;      // staging W: col tid, 8 k (2 float4)
  float acc[8][16] = {};
  float4 xa, wa, wb;

  // prologue: k-block 0 -> LDS[0]
  xa = *(const float4*)(Xp);
  wa = *(const float4*)(Wp);
  wb = *(const float4*)(Wp + 4);
  Xs[0][xq + 0][xr] = xa.x; Xs[0][xq + 1][xr] = xa.y;
  Xs[0][xq + 2][xr] = xa.z; Xs[0][xq + 3][xr] = xa.w;
  Ws[0][0][tid] = wa.x; Ws[0][1][tid] = wa.y; Ws[0][2][tid] = wa.z; Ws[0][3][tid] = wa.w;
  Ws[0][4][tid] = wb.x; Ws[0][5][tid] = wb.y; Ws[0][6][tid] = wb.z; Ws[0][7][tid] = wb.w;

  for (int kt = 0; kt < D_; kt += 8) {      // ascending k blocks
    __syncthreads();
    int buf = (kt >> 3) & 1;
    bool pre = (kt + 8) < D_;
    if (pre) {                               // prefetch next block into regs
      xa = *(const float4*)(Xp + kt + 8);
      wa = *(const float4*)(Wp + kt + 8);
      wb = *(const float4*)(Wp + kt + 12);
    }
    #pragma unroll
    for (int kk = 0; kk < 8; ++kk) {         // ascending k within block
      float xv[8], wv[16];
      *(float4*)(xv)      = *(const float4*)(&Xs[buf][kk][ty * 8]);
      *(float4*)(xv + 4)  = *(const float4*)(&Xs[buf][kk][ty * 8 + 4]);
      *(float4*)(wv)      = *(const float4*)(&Ws[buf][kk][tx * 4]);         // g=0
      *(float4*)(wv + 4)  = *(const float4*)(&Ws[buf][kk][64 + tx * 4]);    // g=1
      *(float4*)(wv + 8)  = *(const float4*)(&Ws[buf][kk][128 + tx * 4]);   // g=2
      *(float4*)(wv + 12) = *(const float4*)(&Ws[buf][kk][192 + tx * 4]);   // g=3
      #pragma unroll
      for (int i = 0; i < 8; ++i)
        #pragma unroll
        for (int j = 0; j < 16; ++j)
          acc[i][j] = fmaf(xv[i], wv[j], acc[i][j]); // single accumulator per element
    }
    if (pre) {                               // write next block to alternate buffer
      int nb = buf ^ 1;
      Xs[nb][xq + 0][xr] = xa.x; Xs[nb][xq + 1][xr] = xa.y;
      Xs[nb][xq + 2][xr] = xa.z; Xs[nb][xq + 3][xr] = xa.w;
      Ws[nb][0][tid] = wa.x; Ws[nb][1][tid] = wa.y; Ws[nb][2][tid] = wa.z; Ws[nb][3][tid] = wa.w;
      Ws[nb][4][tid] = wb.x; Ws[nb][5][tid] = wb.y; Ws[nb][6][tid] = wb.z; Ws[nb][7][tid] = wb.w;
    }
  }

  #pragma unroll
  for (int i = 0; i < 8; ++i) {
    float* pp = P + (size_t)(m0 + ty * 8 + i) * D_ + n0;
    #pragma unroll
    for (int g = 0; g < 4; ++g) {
      float o[4];
      #pragma unroll
      for (int j = 0; j < 4; ++j) {
        float v = acc[i][g * 4 + j] + bias[n0 + g * 64 + tx * 4 + j]; // fp32 bias add, as ref
        if (divq) v = v / SQRTD_F;                                     // IEEE fp32 div, as ref
        o[j] = v;
      }
      *(float4*)(pp + g * 64 + tx * 4) = *(float4*)(o);
    }
  }
}

// ---- scores[r,m] = fmaf-chain_d( Qp[r,d]*Kp[m,d] ), fp32; in-register top-8 + histogram ----
// Block = (local batch lb, 32-row q-tile). 256 thr; group ty (of 32 lanes) owns rows ty*4+i;
// lane tx owns keys {tx*4+j, 128+tx*4+j}. BK=16 double-buffered. Bit-exact fp32 chains.
__global__ __launch_bounds__(256) void kscore32(
    const float* __restrict__ Qp, const float* __restrict__ Kp,
    int* __restrict__ count, int bBase) {
  __shared__ __align__(16) float Ts[2][16][36];   // [buf][kk][row]
  __shared__ __align__(16) float Ks[2][16][260];  // [buf][kk][key]
  __shared__ int hist[256];
  int lb = blockIdx.x / 8, qt = blockIdx.x % 8;
  int b = bBase + lb;
  int tid = threadIdx.x;
  hist[tid] = 0;
  int tx = tid % 32, ty = tid / 32;
  int qr_ = tid / 4, qq = (tid % 4) * 4;  // Q staging (threads 0..127)
  const float* Qrow = Qp + (size_t)(lb * S_ + qt * 32 + qr_) * D_ + qq;
  const float* Krow = Kp + (size_t)(lb * S_ + tid) * D_;
  float acc[4][8] = {};
  float4 qreg = {0, 0, 0, 0};
  float4 kreg0, kreg1, kreg2, kreg3;

  // prologue: load k-block 0, write LDS[0]
  if (tid < 128) qreg = *(const float4*)(Qrow);
  kreg0 = *(const float4*)(Krow);
  kreg1 = *(const float4*)(Krow + 4);
  kreg2 = *(const float4*)(Krow + 8);
  kreg3 = *(const float4*)(Krow + 12);
  if (tid < 128) {
    Ts[0][qq + 0][qr_] = qreg.x; Ts[0][qq + 1][qr_] = qreg.y;
    Ts[0][qq + 2][qr_] = qreg.z; Ts[0][qq + 3][qr_] = qreg.w;
  }
  {
    Ks[0][ 0][tid] = kreg0.x; Ks[0][ 1][tid] = kreg0.y;
    Ks[0][ 2][tid] = kreg0.z; Ks[0][ 3][tid] = kreg0.w;
    Ks[0][ 4][tid] = kreg1.x; Ks[0][ 5][tid] = kreg1.y;
    Ks[0][ 6][tid] = kreg1.z; Ks[0][ 7][tid] = kreg1.w;
    Ks[0][ 8][tid] = kreg2.x; Ks[0][ 9][tid] = kreg2.y;
    Ks[0][10][tid] = kreg2.z; Ks[0][11][tid] = kreg2.w;
    Ks[0][12][tid] = kreg3.x; Ks[0][13][tid] = kreg3.y;
    Ks[0][14][tid] = kreg3.z; Ks[0][15][tid] = kreg3.w;
  }

  for (int kt = 0; kt < D_; kt += 16) {   // ascending d blocks
    __syncthreads();
    int buf = (kt >> 4) & 1;
    bool pre = (kt + 16) < D_;
    if (pre) {
      if (tid < 128) qreg = *(const float4*)(Qrow + kt + 16);
      kreg0 = *(const float4*)(Krow + kt + 16);
      kreg1 = *(const float4*)(Krow + kt + 20);
      kreg2 = *(const float4*)(Krow + kt + 24);
      kreg3 = *(const float4*)(Krow + kt + 28);
    }
    #pragma unroll
    for (int kk = 0; kk < 16; ++kk) {     // ascending d within block
      float tv[4], kv[8];
      *(float4*)(tv)     = *(const float4*)(&Ts[buf][kk][ty * 4]);
      *(float4*)(kv)     = *(const float4*)(&Ks[buf][kk][tx * 4]);
      *(float4*)(kv + 4) = *(const float4*)(&Ks[buf][kk][128 + tx * 4]);
      #pragma unroll
      for (int i = 0; i < 4; ++i)
        #pragma unroll
        for (int j = 0; j < 8; ++j)
          acc[i][j] = fmaf(tv[i], kv[j], acc[i][j]); // single accumulator per element
    }
    if (pre) {
      int nb = buf ^ 1;
      if (tid < 128) {
        Ts[nb][qq + 0][qr_] = qreg.x; Ts[nb][qq + 1][qr_] = qreg.y;
        Ts[nb][qq + 2][qr_] = qreg.z; Ts[nb][qq + 3][qr_] = qreg.w;
      }
      Ks[nb][ 0][tid] = kreg0.x; Ks[nb][ 1][tid] = kreg0.y;
      Ks[nb][ 2][tid] = kreg0.z; Ks[nb][ 3][tid] = kreg0.w;
      Ks[nb][ 4][tid] = kreg1.x; Ks[nb][ 5][tid] = kreg1.y;
      Ks[nb][ 6][tid] = kreg1.z; Ks[nb][ 7][tid] = kreg1.w;
      Ks[nb][ 8][tid] = kreg2.x; Ks[nb][ 9][tid] = kreg2.y;
      Ks[nb][10][tid] = kreg2.z; Ks[nb][11][tid] = kreg2.w;
      Ks[nb][12][tid] = kreg3.x; Ks[nb][13][tid] = kreg3.y;
      Ks[nb][14][tid] = kreg3.z; Ks[nb][15][tid] = kreg3.w;
    }
  }

  // top-8 per row; tie -> lower index (matches jax.lax.top_k on monotone softmax image).
  for (int i = 0; i < 4; ++i) {
    unsigned live = 0xffu;
    #pragma unroll
    for (int it = 0; it < 8; ++it) {
      float bv = -3.4e38f; int bi = 1 << 30;
      #pragma unroll
      for (int j = 0; j < 8; ++j) {
        if ((live >> j) & 1u) {
          float v = acc[i][j];
          int idx = (j < 4) ? (tx * 4 + j) : (128 + tx * 4 + (j - 4));
          if (v > bv || (v == bv && idx < bi)) { bv = v; bi = idx; }
        }
      }
      #pragma unroll
      for (int off = 1; off < 32; off <<= 1) { // closed within the 32-lane group
        float ov = __shfl_xor(bv, off);
        int   oi = __shfl_xor(bi, off);
        if (ov > bv || (ov == bv && oi < bi)) { bv = ov; bi = oi; }
      }
      int owner, jj;
      if (bi < 128) { owner = bi >> 2; jj = bi & 3; }
      else          { owner = (bi - 128) >> 2; jj = 4 + ((bi - 128) & 3); }
      if (tx == owner) live &= ~(1u << jj);
      if (tx == 0) atomicAdd(&hist[bi], 1);
    }
  }
  __syncthreads();
  if (hist[tid] > 0) atomicAdd(&count[(size_t)b * HB + tid], hist[tid]);
}

// ---- final: per-batch top-8 of counts (exact integers), tie-break lower index ----
__global__ __launch_bounds__(64) void kfinal(const int* __restrict__ count, int* __restrict__ out) {
  int b = blockIdx.x;
  int lane = threadIdx.x;
  int c[4];
  #pragma unroll
  for (int j = 0; j < 4; ++j) c[j] = count[(size_t)b * HB + lane + 64 * j];
  #pragma unroll
  for (int it = 0; it < 8; ++it) {
    int bk = -0x7fffffff;
    #pragma unroll
    for (int j = 0; j < 4; ++j) {
      int idx = lane + 64 * j;
      int key = c[j] * 256 + (255 - idx); // removed entries (c=-1) go negative, never win
      if (key > bk) bk = key;
    }
    #pragma unroll
    for (int off = 1; off < 64; off <<= 1) {
      int ok = __shfl_xor(bk, off);
      if (ok > bk) bk = ok;
    }
    int idx = 255 - (bk & 255);
    if (lane == (idx & 63)) c[idx >> 6] = -1;
    if (lane == 0) out[b * K_ + it] = idx;
  }
}

extern "C" void kernel_launch(void* const* d_in, const int* in_sizes, int n_in,
                              void* d_out, int out_size, void* d_ws, size_t ws_size,
                              hipStream_t stream) {
  const float* k_in = (const float*)d_in[0];
  const float* q_in = (const float*)d_in[2];
  const float* Wk   = (const float*)d_in[4];
  const float* bk   = (const float*)d_in[5];
  const float* Wq   = (const float*)d_in[8];
  const float* bq   = (const float*)d_in[9];
  // v/Wv/bv dead; mask all-true; softmax monotone in fp32 (equal scores -> equal attention,
  // same lower-index tie) => top-k on scores. Pipeline = reference verbatim, in fp32 with
  // BLAS-equivalent per-element rounding (single-acc ascending-k FMA chains):
  //   Kp = k_in@Wk^T + bk ; Qp = (q_in@Wq^T + bq) / f32(sqrt(768)) ; scores = Qp@Kp^T.

  char* ws = (char*)d_ws;
  int* cnt = (int*)ws;                 // 512*256*4 = 524288 B
  const size_t offQ = 524288;

  // CB=64: per-chunk working set ~200 MB -> L3-resident (R7 lesson: 400+ MB thrashes L3).
  int CB = 64;
  while (CB > 1 && offQ + 2 * (size_t)CB * S_ * D_ * 4 > ws_size) CB >>= 1;
  const int nchunks = B_ / CB;
  float* Qp = (float*)(ws + offQ);
  float* Kp = Qp + (size_t)CB * S_ * D_;

  hipMemsetAsync(cnt, 0, (size_t)B_ * HB * 4, stream);

  for (int c = 0; c < nchunks; ++c) {
    const float* kc = k_in + (size_t)c * CB * S_ * D_;
    const float* qc = q_in + (size_t)c * CB * S_ * D_;
    // tilesPerInput = (CB*256/128 rows) * (768/256 cols) = CB*6
    kproj32<<<CB * 12, 256, 0, stream>>>(kc, qc, Wk, bk, Wq, bq, Kp, Qp, CB * 6);
    kscore32<<<CB * 8, 256, 0, stream>>>(Qp, Kp, cnt, c * CB);
  }
  kfinal<<<B_, 64, 0, stream>>>(cnt, (int*)d_out);
}